// Round 11
// baseline (839.772 us; speedup 1.0000x reference)
//
#include <hip/hip_runtime.h>
#include <hip/hip_bf16.h>
#include <hip/hip_cooperative_groups.h>
#include <math.h>

namespace cg = cooperative_groups;

typedef __hip_bfloat16 bf16;
typedef short bf16x8 __attribute__((ext_vector_type(8)));
typedef float f32x4 __attribute__((ext_vector_type(4)));

__device__ __forceinline__ float b2f(bf16 v) { return __bfloat162float(v); }
__device__ __forceinline__ bf16 f2b(float v) { return __float2bfloat16(v); }
__device__ __forceinline__ float us2f(unsigned short u) {
  return __uint_as_float(((unsigned)u) << 16);
}
__device__ __forceinline__ unsigned short f2us(float f) {
  bf16 h = __float2bfloat16(f);
  return *reinterpret_cast<unsigned short*>(&h);
}
__device__ __forceinline__ float ldin(const void* p, size_t i, int f32) {
  return f32 ? ((const float*)p)[i] : b2f(((const bf16*)p)[i]);
}

#define CC 192
#define DD 8
#define HH 32
#define WW 32
#define NHEAD 6
#define HDIM 32
#define HID 768
#define NTOK 8192
#define ATT_SCALE 0.17677669529663687f

#define WOFF_TQKV  0
#define WOFF_TOUT  110592
#define WOFF_TFC1  147456
#define WOFF_TFC2  294912
#define WOFF_SQKV  442368
#define WOFF_SPROJ 552960
#define WOFF_SFC1  589824
#define WOFF_SFC2  737280

// ============================ shared-mem union =============================
#define PKS 40
#define PVS 232
struct SmemGemm {            // 27.6 KB
  unsigned short As[128 * 72];
  unsigned short Bs[64 * 72];
};
struct SmemNat {             // 68.3 KB (max)
  unsigned short Ks[224 * PKS];
  unsigned short Vs[32 * PVS];
  unsigned short Qs[64 * PKS];
  unsigned short Ps[64 * PVS];
  float rb[176];
};
struct SmemTA {              // 19.9 KB
  float q[NHEAD][DD][HDIM];
  float k[NHEAD][DD][HDIM];
  float v[NHEAD][DD][HDIM];
  float p[NHEAD][DD][DD];
};
union Smem {
  SmemGemm g;
  SmemNat n;
  SmemTA t;
};

// ============================ kernel arguments =============================
struct KArgs {
  const void *x, *pos;
  const void *t_ln1_g, *t_ln1_b, *t_out_b, *t_ln2_g, *t_ln2_b;
  const void *t_fc1_b, *t_fc2_b, *t_lnf_g, *t_lnf_b;
  const void *s_ln1_g, *s_ln1_b, *s_qkv_b, *s_rpb, *s_proj_b;
  const void *s_ln2_g, *s_ln2_b, *s_fc1_b, *s_fc2_b;
  const void *w0, *w1, *w2, *w3, *w4, *w5, *w6, *w7;
  void* out;
  float* T; float* X1T; bf16* Y; bf16* O; bf16* QKV; bf16* WT;
};

// ============================ device stages ================================
__device__ void st_wconv(const KArgs& a, int f32) {
  for (int idx = blockIdx.x * 256 + threadIdx.x; idx < 884736; idx += gridDim.x * 256) {
    const void* src; int K, N, loc;
    if      (idx < 110592) { src = a.w0; K = 192; N = 576; loc = idx; }
    else if (idx < 147456) { src = a.w1; K = 192; N = 192; loc = idx - 110592; }
    else if (idx < 294912) { src = a.w2; K = 192; N = 768; loc = idx - 147456; }
    else if (idx < 442368) { src = a.w3; K = 768; N = 192; loc = idx - 294912; }
    else if (idx < 552960) { src = a.w4; K = 192; N = 576; loc = idx - 442368; }
    else if (idx < 589824) { src = a.w5; K = 192; N = 192; loc = idx - 552960; }
    else if (idx < 737280) { src = a.w6; K = 192; N = 768; loc = idx - 589824; }
    else                   { src = a.w7; K = 768; N = 192; loc = idx - 737280; }
    int n = loc / K, k = loc - n * K;
    a.WT[idx] = f2b(ldin(src, (size_t)k * N + n, f32));
  }
}

__device__ void st_build_ln1(const KArgs& a, int f32) {
  int w = threadIdx.x >> 6, lane = threadIdx.x & 63;
  for (int row = blockIdx.x * 4 + w; row < NTOK; row += gridDim.x * 4) {
    int d = row & 7, hw = row >> 3;
    float v[3];
#pragma unroll
    for (int e = 0; e < 3; e++) {
      int c = lane + e * 64;
      v[e] = ldin(a.x, (size_t)((c << 3) + d) * 1024 + hw, f32) +
             ldin(a.pos, (size_t)d * CC + c, f32);
    }
    float* tr = a.T + (size_t)row * CC;
#pragma unroll
    for (int e = 0; e < 3; e++) tr[lane + e * 64] = v[e];
    float s = v[0] + v[1] + v[2];
    for (int off = 32; off; off >>= 1) s += __shfl_xor(s, off);
    float mean = s * (1.0f / CC);
    float d0 = v[0] - mean, d1 = v[1] - mean, d2 = v[2] - mean;
    float q = d0 * d0 + d1 * d1 + d2 * d2;
    for (int off = 32; off; off >>= 1) q += __shfl_xor(q, off);
    float rstd = rsqrtf(q * (1.0f / CC) + 1e-5f);
    bf16* o = a.Y + (size_t)row * CC;
    o[lane]       = f2b(d0 * rstd * ldin(a.t_ln1_g, lane, f32)       + ldin(a.t_ln1_b, lane, f32));
    o[lane + 64]  = f2b(d1 * rstd * ldin(a.t_ln1_g, lane + 64, f32)  + ldin(a.t_ln1_b, lane + 64, f32));
    o[lane + 128] = f2b(d2 * rstd * ldin(a.t_ln1_g, lane + 128, f32) + ldin(a.t_ln1_b, lane + 128, f32));
  }
}

__device__ void st_ln(const float* in, bf16* out, const void* g, const void* b, int f32) {
  int w = threadIdx.x >> 6, lane = threadIdx.x & 63;
  for (int row = blockIdx.x * 4 + w; row < NTOK; row += gridDim.x * 4) {
    const float* r = in + (size_t)row * CC;
    float v0 = r[lane], v1 = r[lane + 64], v2 = r[lane + 128];
    float s = v0 + v1 + v2;
    for (int off = 32; off; off >>= 1) s += __shfl_xor(s, off);
    float mean = s * (1.0f / CC);
    float d0 = v0 - mean, d1 = v1 - mean, d2 = v2 - mean;
    float q = d0 * d0 + d1 * d1 + d2 * d2;
    for (int off = 32; off; off >>= 1) q += __shfl_xor(q, off);
    float rstd = rsqrtf(q * (1.0f / CC) + 1e-5f);
    bf16* o = out + (size_t)row * CC;
    o[lane]       = f2b(d0 * rstd * ldin(g, lane, f32)       + ldin(b, lane, f32));
    o[lane + 64]  = f2b(d1 * rstd * ldin(g, lane + 64, f32)  + ldin(b, lane + 64, f32));
    o[lane + 128] = f2b(d2 * rstd * ldin(g, lane + 128, f32) + ldin(b, lane + 128, f32));
  }
}

__device__ void st_epi_ln1(const KArgs& a, int f32) {
  int w = threadIdx.x >> 6, lane = threadIdx.x & 63;
  for (int row = blockIdx.x * 4 + w; row < NTOK; row += gridDim.x * 4) {
    const float* r = a.T + (size_t)row * CC;
    float v0 = r[lane], v1 = r[lane + 64], v2 = r[lane + 128];
    float s = v0 + v1 + v2;
    for (int off = 32; off; off >>= 1) s += __shfl_xor(s, off);
    float mean = s * (1.0f / CC);
    float d0 = v0 - mean, d1 = v1 - mean, d2 = v2 - mean;
    float q = d0 * d0 + d1 * d1 + d2 * d2;
    for (int off = 32; off; off >>= 1) q += __shfl_xor(q, off);
    float rstd = rsqrtf(q * (1.0f / CC) + 1e-5f);
    int d = row & 7, hw = row >> 3;
    int m = d * 1024 + hw;
    float xv[3];
#pragma unroll
    for (int e = 0; e < 3; e++) {
      int c = lane + e * 64;
      float dv = (e == 0 ? d0 : (e == 1 ? d1 : d2));
      float normed = dv * rstd * ldin(a.t_lnf_g, c, f32) + ldin(a.t_lnf_b, c, f32);
      xv[e] = ldin(a.x, (size_t)((c << 3) + d) * 1024 + hw, f32) + normed;
    }
    float* o = a.X1T + (size_t)m * CC;
#pragma unroll
    for (int e = 0; e < 3; e++) o[lane + e * 64] = xv[e];
    float s2 = xv[0] + xv[1] + xv[2];
    for (int off = 32; off; off >>= 1) s2 += __shfl_xor(s2, off);
    float mean2 = s2 * (1.0f / CC);
    float e0 = xv[0] - mean2, e1 = xv[1] - mean2, e2 = xv[2] - mean2;
    float q2 = e0 * e0 + e1 * e1 + e2 * e2;
    for (int off = 32; off; off >>= 1) q2 += __shfl_xor(q2, off);
    float rstd2 = rsqrtf(q2 * (1.0f / CC) + 1e-5f);
    bf16* y = a.Y + (size_t)m * CC;
    y[lane]       = f2b(e0 * rstd2 * ldin(a.s_ln1_g, lane, f32)       + ldin(a.s_ln1_b, lane, f32));
    y[lane + 64]  = f2b(e1 * rstd2 * ldin(a.s_ln1_g, lane + 64, f32)  + ldin(a.s_ln1_b, lane + 64, f32));
    y[lane + 128] = f2b(e2 * rstd2 * ldin(a.s_ln1_g, lane + 128, f32) + ldin(a.s_ln1_b, lane + 128, f32));
  }
}

template <int TM, bool BIAS, bool GELU, bool RES, bool OUTBF, bool FINAL>
__device__ void st_gemm(SmemGemm& sm, const bf16* A, const bf16* WT,
                        const void* bias, const float* R, void* Cout,
                        const float* X2, int N, int K, int nbx, int f32) {
  int tid = threadIdx.x;
  int w = tid >> 6, lane = tid & 63, lm = lane & 15, lk = lane >> 4;
  const unsigned short* Au = reinterpret_cast<const unsigned short*>(A);
  const unsigned short* Wu = reinterpret_cast<const unsigned short*>(WT);
  int njobs = nbx * (NTOK / (TM * 64));
  for (int job = blockIdx.x; job < njobs; job += gridDim.x) {
    __syncthreads();
    int bxk = job % nbx, byk = job / nbx;
    int bm = byk * (TM * 64), bn = bxk * 64;
    f32x4 acc[TM][4];
#pragma unroll
    for (int i = 0; i < TM; i++)
#pragma unroll
      for (int j = 0; j < 4; j++) acc[i][j] = (f32x4){0.f, 0.f, 0.f, 0.f};

    for (int k0 = 0; k0 < K; k0 += 64) {
#pragma unroll
      for (int u = 0; u < TM * 2; u++) {
        int unit = tid + u * 256;
        int row = unit >> 3, seg = unit & 7;
        uint4 v = *reinterpret_cast<const uint4*>(
            &Au[(size_t)(bm + row) * K + k0 + seg * 8]);
        *reinterpret_cast<uint4*>(&sm.As[row * 72 + seg * 8]) = v;
      }
#pragma unroll
      for (int u = 0; u < 2; u++) {
        int unit = tid + u * 256;
        int n = unit >> 3, seg = unit & 7;
        uint4 v = *reinterpret_cast<const uint4*>(
            &Wu[(size_t)(bn + n) * K + k0 + seg * 8]);
        *reinterpret_cast<uint4*>(&sm.Bs[n * 72 + seg * 8]) = v;
      }
      __syncthreads();
#pragma unroll
      for (int kc = 0; kc < 2; kc++) {
        bf16x8 af[TM], bfr[4];
#pragma unroll
        for (int tm = 0; tm < TM; tm++)
          af[tm] = *reinterpret_cast<const bf16x8*>(
              &sm.As[(w * (TM * 16) + tm * 16 + lm) * 72 + kc * 32 + lk * 8]);
#pragma unroll
        for (int tn = 0; tn < 4; tn++)
          bfr[tn] = *reinterpret_cast<const bf16x8*>(
              &sm.Bs[(tn * 16 + lm) * 72 + kc * 32 + lk * 8]);
#pragma unroll
        for (int tm = 0; tm < TM; tm++)
#pragma unroll
          for (int tn = 0; tn < 4; tn++)
            acc[tm][tn] = __builtin_amdgcn_mfma_f32_16x16x32_bf16(
                af[tm], bfr[tn], acc[tm][tn], 0, 0, 0);
      }
      __syncthreads();
    }

#pragma unroll
    for (int tn = 0; tn < 4; tn++) {
      int col = bn + tn * 16 + lm;
      float bv = BIAS ? ldin(bias, col, f32) : 0.f;
#pragma unroll
      for (int tm = 0; tm < TM; tm++) {
        int row0 = bm + w * (TM * 16) + tm * 16 + lk * 4;
#pragma unroll
        for (int r = 0; r < 4; r++) {
          int row = row0 + r;
          float v = acc[tm][tn][r];
          if (BIAS) v += bv;
          if (GELU) v = 0.5f * v * (1.0f + erff(v * 0.70710678118654752f));
          size_t idx = (size_t)row * N + col;
          if (RES) v += R[idx];
          if (FINAL) {
            float o = v + X2[(size_t)row * CC + col];
            if (f32) ((float*)Cout)[(size_t)col * NTOK + row] = o;
            else     ((bf16*)Cout)[(size_t)col * NTOK + row] = f2b(o);
          } else if (OUTBF) {
            ((bf16*)Cout)[idx] = f2b(v);
          } else {
            ((float*)Cout)[idx] = v;
          }
        }
      }
    }
  }
}

__device__ void st_time_attn(SmemTA& sm, const bf16* qkv, bf16* O) {
  bool act = threadIdx.x < 192;
  int head = threadIdx.x >> 5;
  int dd = threadIdx.x & 31;
  for (int n = blockIdx.x; n < 1024; n += gridDim.x) {
    __syncthreads();
    if (act) {
      for (int s = 0; s < DD; s++) {
        const bf16* row = qkv + (size_t)(n * DD + s) * (3 * CC);
        sm.q[head][s][dd] = b2f(row[head * HDIM + dd]);
        sm.k[head][s][dd] = b2f(row[CC + head * HDIM + dd]);
        sm.v[head][s][dd] = b2f(row[2 * CC + head * HDIM + dd]);
      }
    }
    __syncthreads();
    if (act) {
      for (int pair = dd; pair < 64; pair += 32) {
        int sq = pair >> 3, sk = pair & 7;
        float sum = 0.f;
#pragma unroll
        for (int e = 0; e < HDIM; e++) sum += sm.q[head][sq][e] * sm.k[head][sk][e];
        sm.p[head][sq][sk] = sum * ATT_SCALE;
      }
    }
    __syncthreads();
    if (act && dd < DD) {
      float mx = -1e30f;
      for (int sk = 0; sk < DD; sk++) mx = fmaxf(mx, sm.p[head][dd][sk]);
      float sum = 0.f;
      for (int sk = 0; sk < DD; sk++) { float e = expf(sm.p[head][dd][sk] - mx); sm.p[head][dd][sk] = e; sum += e; }
      float inv = 1.0f / sum;
      for (int sk = 0; sk < DD; sk++) sm.p[head][dd][sk] *= inv;
    }
    __syncthreads();
    if (act) {
      for (int sq = 0; sq < DD; sq++) {
        float sum = 0.f;
#pragma unroll
        for (int sk = 0; sk < DD; sk++) sum += sm.p[head][sq][sk] * sm.v[head][sk][dd];
        O[(size_t)(n * DD + sq) * CC + head * HDIM + dd] = f2b(sum);
      }
    }
  }
}

__device__ void st_nat(SmemNat& sm, const bf16* qkv, const void* rpb, bf16* O, int f32) {
  int tid = threadIdx.x;
  for (int job = blockIdx.x; job < 768; job += gridDim.x) {
    __syncthreads();
    int frame = job & 7;
    int rest = job >> 3;
    int h = rest % 6;
    int tile = rest / 6;
    int ty = tile >> 2, tx = tile & 3;
    int base_h = min(max(ty * 8 - 3, 0), HH - 7);
    int base_w = min(max(tx * 8 - 3, 0), WW - 7);

    for (int i = tid; i < 169; i += 256) sm.rb[i] = ldin(rpb, (size_t)h * 169 + i, f32);
    for (int u = tid; u < 784; u += 256) {
      int j = u >> 2, seg = u & 3;
      int a2 = j / 14, bb = j - a2 * 14;
      int ih = min(base_h + a2, HH - 1), iw = min(base_w + bb, WW - 1);
      int mg = frame * 1024 + ih * 32 + iw;
      uint4 v = *reinterpret_cast<const uint4*>(qkv + (size_t)mg * 576 + 192 + h * 32 + seg * 8);
      *reinterpret_cast<uint4*>(&sm.Ks[j * PKS + seg * 8]) = v;
    }
    for (int u = tid; u < 784; u += 256) {
      int j = u >> 2, seg = u & 3;
      int a2 = j / 14, bb = j - a2 * 14;
      int ih = min(base_h + a2, HH - 1), iw = min(base_w + bb, WW - 1);
      int mg = frame * 1024 + ih * 32 + iw;
      uint4 v = *reinterpret_cast<const uint4*>(qkv + (size_t)mg * 576 + 384 + h * 32 + seg * 8);
      unsigned arr[4] = {v.x, v.y, v.z, v.w};
#pragma unroll
      for (int e = 0; e < 4; e++) {
        sm.Vs[(seg * 8 + e * 2) * PVS + j]     = (unsigned short)(arr[e] & 0xffffu);
        sm.Vs[(seg * 8 + e * 2 + 1) * PVS + j] = (unsigned short)(arr[e] >> 16);
      }
    }
    for (int u = tid; u < 32 * (PVS - 196); u += 256) {
      int dd = u / (PVS - 196), c2 = 196 + u % (PVS - 196);
      sm.Vs[dd * PVS + c2] = 0;
    }
    {
      int q = tid >> 2, seg = tid & 3;
      int qy = ty * 8 + (q >> 3), qx = tx * 8 + (q & 7);
      int mg = frame * 1024 + qy * 32 + qx;
      uint4 v = *reinterpret_cast<const uint4*>(qkv + (size_t)mg * 576 + h * 32 + seg * 8);
      *reinterpret_cast<uint4*>(&sm.Qs[q * PKS + seg * 8]) = v;
    }
    __syncthreads();

    int w = tid >> 6;
    int lane = tid & 63;
    int c = lane & 15;
    int lk = lane >> 4;

    bf16x8 aq = *reinterpret_cast<const bf16x8*>(&sm.Qs[(w * 16 + c) * PKS + lk * 8]);
    f32x4 sc[14];
#pragma unroll
    for (int f = 0; f < 14; f++) {
      bf16x8 bk = *reinterpret_cast<const bf16x8*>(&sm.Ks[(f * 16 + c) * PKS + lk * 8]);
      sc[f] = __builtin_amdgcn_mfma_f32_16x16x32_bf16(aq, bk, (f32x4){0.f, 0.f, 0.f, 0.f}, 0, 0, 0);
    }

#pragma unroll
    for (int f = 0; f < 14; f++) {
      int key = f * 16 + c;
      int a2 = key / 14, bb = key - a2 * 14;
      int ih = base_h + a2, iw = base_w + bb;
      bool keyok = key < 196;
#pragma unroll
      for (int r = 0; r < 4; r++) {
        int qloc = w * 16 + lk * 4 + r;
        int qy = ty * 8 + (qloc >> 3), qx = tx * 8 + (qloc & 7);
        int sh = min(max(qy - 3, 0), HH - 7);
        int sw = min(max(qx - 3, 0), WW - 7);
        bool valid = keyok && ((unsigned)(ih - sh) < 7u) && ((unsigned)(iw - sw) < 7u);
        int bidx = valid ? (ih - qy + 6) * 13 + (iw - qx + 6) : 0;
        float s = sc[f][r] * ATT_SCALE + sm.rb[bidx];
        sc[f][r] = valid ? s : -1e30f;
      }
    }

    float smx[4];
#pragma unroll
    for (int r = 0; r < 4; r++) {
      float m = sc[0][r];
#pragma unroll
      for (int f = 1; f < 14; f++) m = fmaxf(m, sc[f][r]);
      for (int off = 8; off; off >>= 1) m = fmaxf(m, __shfl_xor(m, off));
      float s = 0.f;
#pragma unroll
      for (int f = 0; f < 14; f++) { float e = __expf(sc[f][r] - m); sc[f][r] = e; s += e; }
      for (int off = 8; off; off >>= 1) s += __shfl_xor(s, off);
      smx[r] = 1.0f / s;
    }
#pragma unroll
    for (int f = 0; f < 14; f++)
#pragma unroll
      for (int r = 0; r < 4; r++)
        sm.Ps[(w * 16 + lk * 4 + r) * PVS + f * 16 + c] = f2us(sc[f][r] * smx[r]);
    __syncthreads();

    f32x4 oacc[2] = {(f32x4){0.f, 0.f, 0.f, 0.f}, (f32x4){0.f, 0.f, 0.f, 0.f}};
#pragma unroll
    for (int kt = 0; kt < 7; kt++) {
      bf16x8 ap = *reinterpret_cast<const bf16x8*>(&sm.Ps[(w * 16 + c) * PVS + kt * 32 + lk * 8]);
#pragma unroll
      for (int dt = 0; dt < 2; dt++) {
        bf16x8 bv = *reinterpret_cast<const bf16x8*>(&sm.Vs[(dt * 16 + c) * PVS + kt * 32 + lk * 8]);
        oacc[dt] = __builtin_amdgcn_mfma_f32_16x16x32_bf16(ap, bv, oacc[dt], 0, 0, 0);
      }
    }
#pragma unroll
    for (int dt = 0; dt < 2; dt++)
#pragma unroll
      for (int r = 0; r < 4; r++) {
        int qloc = w * 16 + lk * 4 + r;
        int qy = ty * 8 + (qloc >> 3), qx = tx * 8 + (qloc & 7);
        int mg = frame * 1024 + qy * 32 + qx;
        O[(size_t)mg * CC + h * 32 + dt * 16 + c] = f2b(oacc[dt][r]);
      }
  }
}

// ============================ mega kernel ==================================
__global__ void __launch_bounds__(256, 2) mega_kernel(KArgs a) {
  __shared__ __align__(16) Smem sm;
  __shared__ int cnt[4];
  int f32;
  {
    float v = fabsf(us2f(((const unsigned short*)a.x)[threadIdx.x]));
    bool insane = !((v == 0.0f) || (v > 9.5e-7f && v < 64.0f));
    unsigned long long m = __ballot(insane);
    if ((threadIdx.x & 63) == 0) cnt[threadIdx.x >> 6] = __popcll(m);
  }
  __syncthreads();
  f32 = (cnt[0] + cnt[1] + cnt[2] + cnt[3]) > 32;

  cg::grid_group grid = cg::this_grid();

  st_wconv(a, f32);                                       grid.sync();
  st_build_ln1(a, f32);                                   grid.sync();
  st_gemm<2, false, false, false, true, false>(sm.g, a.Y, a.WT + WOFF_TQKV,
      nullptr, nullptr, a.QKV, nullptr, 3 * CC, CC, 9, f32);      grid.sync();
  st_time_attn(sm.t, a.QKV, a.O);                         grid.sync();
  st_gemm<1, true, false, true, false, false>(sm.g, a.O, a.WT + WOFF_TOUT,
      a.t_out_b, a.T, a.T, nullptr, CC, CC, 3, f32);              grid.sync();
  st_ln(a.T, a.Y, a.t_ln2_g, a.t_ln2_b, f32);             grid.sync();
  st_gemm<2, true, true, false, true, false>(sm.g, a.Y, a.WT + WOFF_TFC1,
      a.t_fc1_b, nullptr, a.QKV /*Hb*/, nullptr, HID, CC, 12, f32); grid.sync();
  st_gemm<1, true, false, true, false, false>(sm.g, a.QKV /*Hb*/, a.WT + WOFF_TFC2,
      a.t_fc2_b, a.T, a.T, nullptr, CC, HID, 3, f32);             grid.sync();
  st_epi_ln1(a, f32);                                     grid.sync();
  st_gemm<2, true, false, false, true, false>(sm.g, a.Y, a.WT + WOFF_SQKV,
      a.s_qkv_b, nullptr, a.QKV, nullptr, 3 * CC, CC, 9, f32);    grid.sync();
  st_nat(sm.n, a.QKV, a.s_rpb, a.O, f32);                 grid.sync();
  st_gemm<1, true, false, true, false, false>(sm.g, a.O, a.WT + WOFF_SPROJ,
      a.s_proj_b, a.X1T, a.T, nullptr, CC, CC, 3, f32);           grid.sync();
  st_ln(a.T, a.Y, a.s_ln2_g, a.s_ln2_b, f32);             grid.sync();
  st_gemm<2, true, true, false, true, false>(sm.g, a.Y, a.WT + WOFF_SFC1,
      a.s_fc1_b, nullptr, a.QKV /*Hb*/, nullptr, HID, CC, 12, f32); grid.sync();
  st_gemm<1, true, false, true, false, true>(sm.g, a.QKV /*Hb*/, a.WT + WOFF_SFC2,
      a.s_fc2_b, a.T, a.out, a.X1T, CC, HID, 3, f32);
}

// ===================== fallback wrappers (r10 path, 15 launches) ==========
__device__ int probe_local(const unsigned short* xu) {
  __shared__ int cnt[4];
  float v = fabsf(us2f(xu[threadIdx.x]));
  bool insane = !((v == 0.0f) || (v > 9.5e-7f && v < 64.0f));
  unsigned long long m = __ballot(insane);
  if ((threadIdx.x & 63) == 0) cnt[threadIdx.x >> 6] = __popcll(m);
  __syncthreads();
  int f = (cnt[0] + cnt[1] + cnt[2] + cnt[3]) > 32;
  __syncthreads();
  return f;
}
__global__ void __launch_bounds__(256, 2) k_wconv(KArgs a) {
  int f32 = probe_local((const unsigned short*)a.x);
  st_wconv(a, f32);
}
__global__ void __launch_bounds__(256, 2) k_build(KArgs a) {
  int f32 = probe_local((const unsigned short*)a.x);
  st_build_ln1(a, f32);
}
__global__ void __launch_bounds__(256, 2) k_ln2t(KArgs a) {
  int f32 = probe_local((const unsigned short*)a.x);
  st_ln(a.T, a.Y, a.t_ln2_g, a.t_ln2_b, f32);
}
__global__ void __launch_bounds__(256, 2) k_ln2s(KArgs a) {
  int f32 = probe_local((const unsigned short*)a.x);
  st_ln(a.T, a.Y, a.s_ln2_g, a.s_ln2_b, f32);
}
__global__ void __launch_bounds__(256, 2) k_epi(KArgs a) {
  int f32 = probe_local((const unsigned short*)a.x);
  st_epi_ln1(a, f32);
}
__global__ void __launch_bounds__(256, 2) k_tattn(KArgs a) {
  __shared__ __align__(16) SmemTA sm;
  st_time_attn(sm, a.QKV, a.O);
}
__global__ void __launch_bounds__(256, 2) k_nat(KArgs a) {
  __shared__ __align__(16) SmemNat sm;
  int f32 = probe_local((const unsigned short*)a.x);
  st_nat(sm, a.QKV, a.s_rpb, a.O, f32);
}
__global__ void __launch_bounds__(256, 2) k_g_tqkv(KArgs a) {
  __shared__ __align__(16) SmemGemm sm;
  int f32 = probe_local((const unsigned short*)a.x);
  st_gemm<2, false, false, false, true, false>(sm, a.Y, a.WT + WOFF_TQKV,
      nullptr, nullptr, a.QKV, nullptr, 3 * CC, CC, 9, f32);
}
__global__ void __launch_bounds__(256, 2) k_g_tout(KArgs a) {
  __shared__ __align__(16) SmemGemm sm;
  int f32 = probe_local((const unsigned short*)a.x);
  st_gemm<1, true, false, true, false, false>(sm, a.O, a.WT + WOFF_TOUT,
      a.t_out_b, a.T, a.T, nullptr, CC, CC, 3, f32);
}
__global__ void __launch_bounds__(256, 2) k_g_tfc1(KArgs a) {
  __shared__ __align__(16) SmemGemm sm;
  int f32 = probe_local((const unsigned short*)a.x);
  st_gemm<2, true, true, false, true, false>(sm, a.Y, a.WT + WOFF_TFC1,
      a.t_fc1_b, nullptr, a.QKV, nullptr, HID, CC, 12, f32);
}
__global__ void __launch_bounds__(256, 2) k_g_tfc2(KArgs a) {
  __shared__ __align__(16) SmemGemm sm;
  int f32 = probe_local((const unsigned short*)a.x);
  st_gemm<1, true, false, true, false, false>(sm, a.QKV, a.WT + WOFF_TFC2,
      a.t_fc2_b, a.T, a.T, nullptr, CC, HID, 3, f32);
}
__global__ void __launch_bounds__(256, 2) k_g_sqkv(KArgs a) {
  __shared__ __align__(16) SmemGemm sm;
  int f32 = probe_local((const unsigned short*)a.x);
  st_gemm<2, true, false, false, true, false>(sm, a.Y, a.WT + WOFF_SQKV,
      a.s_qkv_b, nullptr, a.QKV, nullptr, 3 * CC, CC, 9, f32);
}
__global__ void __launch_bounds__(256, 2) k_g_sproj(KArgs a) {
  __shared__ __align__(16) SmemGemm sm;
  int f32 = probe_local((const unsigned short*)a.x);
  st_gemm<1, true, false, true, false, false>(sm, a.O, a.WT + WOFF_SPROJ,
      a.s_proj_b, a.X1T, a.T, nullptr, CC, CC, 3, f32);
}
__global__ void __launch_bounds__(256, 2) k_g_sfc1(KArgs a) {
  __shared__ __align__(16) SmemGemm sm;
  int f32 = probe_local((const unsigned short*)a.x);
  st_gemm<2, true, true, false, true, false>(sm, a.Y, a.WT + WOFF_SFC1,
      a.s_fc1_b, nullptr, a.QKV, nullptr, HID, CC, 12, f32);
}
__global__ void __launch_bounds__(256, 2) k_g_sfc2(KArgs a) {
  __shared__ __align__(16) SmemGemm sm;
  int f32 = probe_local((const unsigned short*)a.x);
  st_gemm<1, true, false, true, false, true>(sm, a.QKV, a.WT + WOFF_SFC2,
      a.s_fc2_b, a.T, a.out, a.X1T, CC, HID, 3, f32);
}

// ============================ host launcher ================================
extern "C" void kernel_launch(void* const* d_in, const int* in_sizes, int n_in,
                              void* d_out, int out_size, void* d_ws, size_t ws_size,
                              hipStream_t stream) {
  float* ws = (float*)d_ws;
  const size_t SZ = (size_t)NTOK * CC;
  const size_t need = (5 * SZ + 4 + 442368 + 16) * sizeof(float);
  if (ws_size < need) return;

  KArgs a;
  a.x       = d_in[0];  a.pos     = d_in[1];
  a.t_ln1_g = d_in[2];  a.t_ln1_b = d_in[3];
  a.w0      = d_in[4];               // t_qkv_w
  a.w1      = d_in[5];  a.t_out_b = d_in[6];   // t_out_w
  a.t_ln2_g = d_in[7];  a.t_ln2_b = d_in[8];
  a.w2      = d_in[9];  a.t_fc1_b = d_in[10];  // t_fc1_w
  a.w3      = d_in[11]; a.t_fc2_b = d_in[12];  // t_fc2_w
  a.t_lnf_g = d_in[13]; a.t_lnf_b = d_in[14];
  a.s_ln1_g = d_in[15]; a.s_ln1_b = d_in[16];
  a.w4      = d_in[17]; a.s_qkv_b = d_in[18];  // s_qkv_w
  a.s_rpb   = d_in[19];
  a.w5      = d_in[20]; a.s_proj_b = d_in[21]; // s_proj_w
  a.s_ln2_g = d_in[22]; a.s_ln2_b = d_in[23];
  a.w6      = d_in[24]; a.s_fc1_b = d_in[25];  // s_fc1_w
  a.w7      = d_in[26]; a.s_fc2_b = d_in[27];  // s_fc2_w
  a.out = d_out;
  a.T   = ws;
  a.X1T = ws + SZ;
  a.Y   = (bf16*)(ws + 2 * SZ);
  a.O   = (bf16*)(ws + 2 * SZ + SZ / 2);
  a.QKV = (bf16*)(ws + 3 * SZ);
  a.WT  = (bf16*)(ws + 5 * SZ + 4);

  // ---- cooperative mega-kernel path ----
  int dev = 0, coop = 0;
  hipGetDevice(&dev);
  hipDeviceGetAttribute(&coop, hipDeviceAttributeCooperativeLaunch, dev);
  if (coop) {
    int maxBlk = 0;
    if (hipOccupancyMaxActiveBlocksPerMultiprocessor(&maxBlk, mega_kernel, 256, 0)
            == hipSuccess && maxBlk >= 1) {
      int gridSz = maxBlk * 256;
      if (gridSz > 512) gridSz = 512;
      void* params[] = { (void*)&a };
      if (hipLaunchCooperativeKernel(mega_kernel, dim3(gridSz), dim3(256),
                                     params, 0u, stream) == hipSuccess)
        return;
    }
  }

  // ---- fallback: proven 15-dispatch path ----
  dim3 blk(256);
  k_wconv <<<3456, blk, 0, stream>>>(a);
  k_build <<<512, blk, 0, stream>>>(a);
  k_g_tqkv<<<576, blk, 0, stream>>>(a);
  k_tattn <<<512, blk, 0, stream>>>(a);
  k_g_tout<<<384, blk, 0, stream>>>(a);
  k_ln2t  <<<512, blk, 0, stream>>>(a);
  k_g_tfc1<<<768, blk, 0, stream>>>(a);
  k_g_tfc2<<<384, blk, 0, stream>>>(a);
  k_epi   <<<512, blk, 0, stream>>>(a);
  k_g_sqkv<<<576, blk, 0, stream>>>(a);
  k_nat   <<<768, blk, 0, stream>>>(a);
  k_g_sproj<<<384, blk, 0, stream>>>(a);
  k_ln2s  <<<512, blk, 0, stream>>>(a);
  k_g_sfc1<<<768, blk, 0, stream>>>(a);
  k_g_sfc2<<<384, blk, 0, stream>>>(a);
}

// Round 12
// 272.426 us; speedup vs baseline: 3.0826x; 3.0826x over previous
//
#include <hip/hip_runtime.h>
#include <hip/hip_bf16.h>
#include <math.h>

typedef __hip_bfloat16 bf16;
typedef short bf16x8 __attribute__((ext_vector_type(8)));
typedef float f32x4 __attribute__((ext_vector_type(4)));

__device__ __forceinline__ float b2f(bf16 v) { return __bfloat162float(v); }
__device__ __forceinline__ bf16 f2b(float v) { return __float2bfloat16(v); }
__device__ __forceinline__ float us2f(unsigned short u) {
  return __uint_as_float(((unsigned)u) << 16);
}
__device__ __forceinline__ unsigned short f2us(float f) {
  bf16 h = __float2bfloat16(f);
  return *reinterpret_cast<unsigned short*>(&h);
}
__device__ __forceinline__ float ldin(const void* p, size_t i, int f32) {
  return f32 ? ((const float*)p)[i] : b2f(((const bf16*)p)[i]);
}

#define CC 192
#define DD 8
#define HH 32
#define WW 32
#define NHEAD 6
#define HDIM 32
#define HID 768
#define NTOK 8192
#define ATT_SCALE 0.17677669529663687f

#define WOFF_TQKV  0
#define WOFF_TOUT  110592
#define WOFF_TFC1  147456
#define WOFF_TFC2  294912
#define WOFF_SQKV  442368
#define WOFF_SPROJ 552960
#define WOFF_SFC1  589824
#define WOFF_SFC2  737280

// ---------------------------------------------------------------------------
// Fused prep: blocks [0,216) do coalesced LDS-tiled weight transpose
// (64x64 tiles; read coalesced over n, write coalesced over k);
// blocks [216, 216+2048) do build_ln1 (T = x+pos; Y = LN(T)).
// Dtype flag computed per-block from x's first 256 halfwords (L2-hot);
// block 0 publishes it for subsequent kernels.
// ---------------------------------------------------------------------------
__global__ void __launch_bounds__(256) prep_kernel(
    const unsigned short* __restrict__ xu,
    const void* w0, const void* w1, const void* w2, const void* w3,
    const void* w4, const void* w5, const void* w6, const void* w7,
    bf16* __restrict__ WT, int* __restrict__ flag,
    const void* __restrict__ pos,
    const void* __restrict__ g, const void* __restrict__ b,
    float* __restrict__ T, bf16* __restrict__ Y) {
  __shared__ int cnt[4];
  __shared__ unsigned short tile_s[64 * 66];
  {
    float v = fabsf(us2f(xu[threadIdx.x]));
    bool insane = !((v == 0.0f) || (v > 9.5e-7f && v < 64.0f));
    unsigned long long m = __ballot(insane);
    if ((threadIdx.x & 63) == 0) cnt[threadIdx.x >> 6] = __popcll(m);
  }
  __syncthreads();
  int f32 = (cnt[0] + cnt[1] + cnt[2] + cnt[3]) > 32;
  if (blockIdx.x == 0 && threadIdx.x == 0) *flag = f32;

  int blk = blockIdx.x;
  int w = threadIdx.x >> 6, lane = threadIdx.x & 63;

  if (blk < 216) {
    // ---- weight transpose tile ----
    const int cumt[8] = {27, 36, 72, 108, 135, 144, 180, 216};
    const int Karr[8] = {192, 192, 192, 768, 192, 192, 192, 768};
    const int Narr[8] = {576, 192, 768, 192, 576, 192, 768, 192};
    const int warr[8] = {WOFF_TQKV, WOFF_TOUT, WOFF_TFC1, WOFF_TFC2,
                         WOFF_SQKV, WOFF_SPROJ, WOFF_SFC1, WOFF_SFC2};
    const void* srcs[8] = {w0, w1, w2, w3, w4, w5, w6, w7};
    int m = 0;
    while (blk >= cumt[m]) m++;
    int lt = blk - (m ? cumt[m - 1] : 0);
    int K = Karr[m], N = Narr[m];
    int ncol = N >> 6;
    int kt = lt / ncol, nt = lt - kt * ncol;
    int k0 = kt * 64, n0 = nt * 64;
    const void* src = srcs[m];
#pragma unroll
    for (int i = 0; i < 16; i++) {
      int k = w * 16 + i;
      tile_s[k * 66 + lane] = f2us(ldin(src, (size_t)(k0 + k) * N + n0 + lane, f32));
    }
    __syncthreads();
    unsigned short* dst = reinterpret_cast<unsigned short*>(WT) + warr[m];
#pragma unroll
    for (int i = 0; i < 16; i++) {
      int n = w * 16 + i;
      dst[(size_t)(n0 + n) * K + k0 + lane] = tile_s[lane * 66 + n];
    }
    return;
  }

  // ---- build_ln1 ----
  int row = (blk - 216) * 4 + w;
  if (row >= NTOK) return;
  int d = row & 7, hw = row >> 3;
  float v[3];
#pragma unroll
  for (int e = 0; e < 3; e++) {
    int c = lane + e * 64;
    v[e] = ldin(xu, (size_t)((c << 3) + d) * 1024 + hw, f32) +
           ldin(pos, (size_t)d * CC + c, f32);
  }
  float* tr = T + (size_t)row * CC;
#pragma unroll
  for (int e = 0; e < 3; e++) tr[lane + e * 64] = v[e];
  float s = v[0] + v[1] + v[2];
  for (int off = 32; off; off >>= 1) s += __shfl_xor(s, off);
  float mean = s * (1.0f / CC);
  float d0 = v[0] - mean, d1 = v[1] - mean, d2 = v[2] - mean;
  float q = d0 * d0 + d1 * d1 + d2 * d2;
  for (int off = 32; off; off >>= 1) q += __shfl_xor(q, off);
  float rstd = rsqrtf(q * (1.0f / CC) + 1e-5f);
  bf16* o = Y + (size_t)row * CC;
  o[lane]       = f2b(d0 * rstd * ldin(g, lane, f32)       + ldin(b, lane, f32));
  o[lane + 64]  = f2b(d1 * rstd * ldin(g, lane + 64, f32)  + ldin(b, lane + 64, f32));
  o[lane + 128] = f2b(d2 * rstd * ldin(g, lane + 128, f32) + ldin(b, lane + 128, f32));
}

// ---------------------------------------------------------------------------
// LayerNorm (standalone, proven): fp32 in, bf16 out
// ---------------------------------------------------------------------------
__global__ void ln_kernel(const float* __restrict__ in, bf16* __restrict__ out,
                          const void* __restrict__ g, const void* __restrict__ b,
                          int rows, const int* __restrict__ dfl) {
  int f32 = *dfl;
  int wave = (blockIdx.x * blockDim.x + threadIdx.x) >> 6;
  int lane = threadIdx.x & 63;
  if (wave >= rows) return;
  const float* r = in + (size_t)wave * CC;
  float v0 = r[lane], v1 = r[lane + 64], v2 = r[lane + 128];
  float s = v0 + v1 + v2;
  for (int off = 32; off; off >>= 1) s += __shfl_xor(s, off);
  float mean = s * (1.0f / CC);
  float d0 = v0 - mean, d1 = v1 - mean, d2 = v2 - mean;
  float q = d0 * d0 + d1 * d1 + d2 * d2;
  for (int off = 32; off; off >>= 1) q += __shfl_xor(q, off);
  float rstd = rsqrtf(q * (1.0f / CC) + 1e-5f);
  bf16* o = out + (size_t)wave * CC;
  o[lane]       = f2b(d0 * rstd * ldin(g, lane, f32)       + ldin(b, lane, f32));
  o[lane + 64]  = f2b(d1 * rstd * ldin(g, lane + 64, f32)  + ldin(b, lane + 64, f32));
  o[lane + 128] = f2b(d2 * rstd * ldin(g, lane + 128, f32) + ldin(b, lane + 128, f32));
}

// ---------------------------------------------------------------------------
// MFMA GEMM (proven r7): A bf16 [M,K], WT bf16 [N,K]. BK=64. TM in {1,2}.
// FINAL: dst[col*NTOK+row] = v + X2[row*CC+col] (dtype by flag)
// ---------------------------------------------------------------------------
template <int TM, bool BIAS, bool GELU, bool RES, bool OUTBF, bool FINAL>
__global__ void gemm_kernel(const bf16* __restrict__ A, const bf16* __restrict__ WT,
                            const void* __restrict__ bias, const float* __restrict__ R,
                            void* __restrict__ Cout, const float* __restrict__ X2,
                            int M, int N, int K, const int* __restrict__ dfl) {
  int f32 = *dfl;
  __shared__ __align__(16) unsigned short As[TM * 64 * 72];
  __shared__ __align__(16) unsigned short Bs[64 * 72];
  int bm = blockIdx.y * (TM * 64), bn = blockIdx.x * 64;
  int tid = threadIdx.x;
  int w = tid >> 6;
  int lane = tid & 63;
  int lm = lane & 15;
  int lk = lane >> 4;

  f32x4 acc[TM][4];
#pragma unroll
  for (int i = 0; i < TM; i++)
#pragma unroll
    for (int j = 0; j < 4; j++) acc[i][j] = (f32x4){0.f, 0.f, 0.f, 0.f};

  const unsigned short* Au = reinterpret_cast<const unsigned short*>(A);
  const unsigned short* Wu = reinterpret_cast<const unsigned short*>(WT);

  for (int k0 = 0; k0 < K; k0 += 64) {
#pragma unroll
    for (int u = 0; u < TM * 2; u++) {
      int unit = tid + u * 256;
      int row = unit >> 3, seg = unit & 7;
      uint4 v = *reinterpret_cast<const uint4*>(
          &Au[(size_t)(bm + row) * K + k0 + seg * 8]);
      *reinterpret_cast<uint4*>(&As[row * 72 + seg * 8]) = v;
    }
#pragma unroll
    for (int u = 0; u < 2; u++) {
      int unit = tid + u * 256;
      int n = unit >> 3, seg = unit & 7;
      uint4 v = *reinterpret_cast<const uint4*>(
          &Wu[(size_t)(bn + n) * K + k0 + seg * 8]);
      *reinterpret_cast<uint4*>(&Bs[n * 72 + seg * 8]) = v;
    }
    __syncthreads();

#pragma unroll
    for (int kc = 0; kc < 2; kc++) {
      bf16x8 af[TM], bfr[4];
#pragma unroll
      for (int tm = 0; tm < TM; tm++)
        af[tm] = *reinterpret_cast<const bf16x8*>(
            &As[(w * (TM * 16) + tm * 16 + lm) * 72 + kc * 32 + lk * 8]);
#pragma unroll
      for (int tn = 0; tn < 4; tn++)
        bfr[tn] = *reinterpret_cast<const bf16x8*>(
            &Bs[(tn * 16 + lm) * 72 + kc * 32 + lk * 8]);
#pragma unroll
      for (int tm = 0; tm < TM; tm++)
#pragma unroll
        for (int tn = 0; tn < 4; tn++)
          acc[tm][tn] = __builtin_amdgcn_mfma_f32_16x16x32_bf16(
              af[tm], bfr[tn], acc[tm][tn], 0, 0, 0);
    }
    __syncthreads();
  }

#pragma unroll
  for (int tn = 0; tn < 4; tn++) {
    int col = bn + tn * 16 + lm;
    float bv = BIAS ? ldin(bias, col, f32) : 0.f;
#pragma unroll
    for (int tm = 0; tm < TM; tm++) {
      int row0 = bm + w * (TM * 16) + tm * 16 + lk * 4;
#pragma unroll
      for (int r = 0; r < 4; r++) {
        int row = row0 + r;
        float v = acc[tm][tn][r];
        if (BIAS) v += bv;
        if (GELU) v = 0.5f * v * (1.0f + erff(v * 0.70710678118654752f));
        size_t idx = (size_t)row * N + col;
        if (RES) v += R[idx];
        if (FINAL) {
          float o = v + X2[(size_t)row * CC + col];
          if (f32) ((float*)Cout)[(size_t)col * NTOK + row] = o;
          else     ((bf16*)Cout)[(size_t)col * NTOK + row] = f2b(o);
        } else if (OUTBF) {
          ((bf16*)Cout)[idx] = f2b(v);
        } else {
          ((float*)Cout)[idx] = v;
        }
      }
    }
  }
}

// ---------------------------------------------------------------------------
// Time attention (proven): one block per sequence n (1024), 192 threads
// ---------------------------------------------------------------------------
__global__ void time_attn_kernel(const bf16* __restrict__ qkv, bf16* __restrict__ O) {
  __shared__ float q[NHEAD][DD][HDIM];
  __shared__ float k[NHEAD][DD][HDIM];
  __shared__ float v[NHEAD][DD][HDIM];
  __shared__ float p[NHEAD][DD][DD];
  int n = blockIdx.x;
  int head = threadIdx.x >> 5;
  int dd = threadIdx.x & 31;
  for (int s = 0; s < DD; s++) {
    const bf16* row = qkv + (size_t)(n * DD + s) * (3 * CC);
    q[head][s][dd] = b2f(row[head * HDIM + dd]);
    k[head][s][dd] = b2f(row[CC + head * HDIM + dd]);
    v[head][s][dd] = b2f(row[2 * CC + head * HDIM + dd]);
  }
  __syncthreads();
  for (int pair = dd; pair < 64; pair += 32) {
    int sq = pair >> 3, sk = pair & 7;
    float sum = 0.f;
#pragma unroll
    for (int e = 0; e < HDIM; e++) sum += q[head][sq][e] * k[head][sk][e];
    p[head][sq][sk] = sum * ATT_SCALE;
  }
  __syncthreads();
  if (dd < DD) {
    float mx = -1e30f;
    for (int sk = 0; sk < DD; sk++) mx = fmaxf(mx, p[head][dd][sk]);
    float sum = 0.f;
    for (int sk = 0; sk < DD; sk++) { float e = expf(p[head][dd][sk] - mx); p[head][dd][sk] = e; sum += e; }
    float inv = 1.0f / sum;
    for (int sk = 0; sk < DD; sk++) p[head][dd][sk] *= inv;
  }
  __syncthreads();
  for (int sq = 0; sq < DD; sq++) {
    float sum = 0.f;
#pragma unroll
    for (int sk = 0; sk < DD; sk++) sum += p[head][sq][sk] * v[head][sk][dd];
    O[(size_t)(n * DD + sq) * CC + head * HDIM + dd] = f2b(sum);
  }
}

// ---------------------------------------------------------------------------
// Fused time epilogue + space ln1 (proven r7)
// ---------------------------------------------------------------------------
__global__ void epi_ln1_kernel(const float* __restrict__ T, const void* __restrict__ x,
                               const void* __restrict__ gf, const void* __restrict__ bf,
                               const void* __restrict__ g1, const void* __restrict__ b1,
                               float* __restrict__ X1T, bf16* __restrict__ Y,
                               const int* __restrict__ dfl) {
  int f32 = *dfl;
  int wave = (blockIdx.x * blockDim.x + threadIdx.x) >> 6;
  int lane = threadIdx.x & 63;
  if (wave >= NTOK) return;
  const float* r = T + (size_t)wave * CC;
  float v0 = r[lane], v1 = r[lane + 64], v2 = r[lane + 128];
  float s = v0 + v1 + v2;
  for (int off = 32; off; off >>= 1) s += __shfl_xor(s, off);
  float mean = s * (1.0f / CC);
  float d0 = v0 - mean, d1 = v1 - mean, d2 = v2 - mean;
  float q = d0 * d0 + d1 * d1 + d2 * d2;
  for (int off = 32; off; off >>= 1) q += __shfl_xor(q, off);
  float rstd = rsqrtf(q * (1.0f / CC) + 1e-5f);
  int d = wave & 7, hw = wave >> 3;
  int m = d * 1024 + hw;
  float xv[3];
#pragma unroll
  for (int e = 0; e < 3; e++) {
    int c = lane + e * 64;
    float dv = (e == 0 ? d0 : (e == 1 ? d1 : d2));
    float normed = dv * rstd * ldin(gf, c, f32) + ldin(bf, c, f32);
    xv[e] = ldin(x, (size_t)((c << 3) + d) * 1024 + hw, f32) + normed;
  }
  float* o = X1T + (size_t)m * CC;
#pragma unroll
  for (int e = 0; e < 3; e++) o[lane + e * 64] = xv[e];
  float s2 = xv[0] + xv[1] + xv[2];
  for (int off = 32; off; off >>= 1) s2 += __shfl_xor(s2, off);
  float mean2 = s2 * (1.0f / CC);
  float e0 = xv[0] - mean2, e1 = xv[1] - mean2, e2 = xv[2] - mean2;
  float q2 = e0 * e0 + e1 * e1 + e2 * e2;
  for (int off = 32; off; off >>= 1) q2 += __shfl_xor(q2, off);
  float rstd2 = rsqrtf(q2 * (1.0f / CC) + 1e-5f);
  bf16* y = Y + (size_t)m * CC;
  y[lane]       = f2b(e0 * rstd2 * ldin(g1, lane, f32)       + ldin(b1, lane, f32));
  y[lane + 64]  = f2b(e1 * rstd2 * ldin(g1, lane + 64, f32)  + ldin(b1, lane + 64, f32));
  y[lane + 128] = f2b(e2 * rstd2 * ldin(g1, lane + 128, f32) + ldin(b1, lane + 128, f32));
}

// ---------------------------------------------------------------------------
// MFMA NAT attention (proven r6). Block = (frame, 8x8 tile, head), 768 blocks.
// ---------------------------------------------------------------------------
#define NKEY 224
#define PKS 40
#define PVS 232
__global__ void nat_attn_kernel(const bf16* __restrict__ qkv, const void* __restrict__ rpb,
                                bf16* __restrict__ O, const int* __restrict__ dfl) {
  int f32 = *dfl;
  __shared__ __align__(16) unsigned short Ks[NKEY * PKS];
  __shared__ __align__(16) unsigned short Vs[32 * PVS];
  __shared__ __align__(16) unsigned short Qs[64 * PKS];
  __shared__ __align__(16) unsigned short Ps[64 * PVS];
  __shared__ float rb[176];

  int blk = blockIdx.x;
  int frame = blk & 7;
  int rest = blk >> 3;
  int h = rest % 6;
  int tile = rest / 6;
  int ty = tile >> 2, tx = tile & 3;
  int base_h = min(max(ty * 8 - 3, 0), HH - 7);
  int base_w = min(max(tx * 8 - 3, 0), WW - 7);

  int tid = threadIdx.x;

  for (int i = tid; i < 169; i += 256) rb[i] = ldin(rpb, (size_t)h * 169 + i, f32);
  for (int u = tid; u < 784; u += 256) {
    int j = u >> 2, seg = u & 3;
    int a = j / 14, bb = j - a * 14;
    int ih = min(base_h + a, HH - 1), iw = min(base_w + bb, WW - 1);
    int mg = frame * 1024 + ih * 32 + iw;
    uint4 v = *reinterpret_cast<const uint4*>(qkv + (size_t)mg * 576 + 192 + h * 32 + seg * 8);
    *reinterpret_cast<uint4*>(&Ks[j * PKS + seg * 8]) = v;
  }
  for (int u = tid; u < 784; u += 256) {
    int j = u >> 2, seg = u & 3;
    int a = j / 14, bb = j - a * 14;
    int ih = min(base_h + a, HH - 1), iw = min(base_w + bb, WW - 1);
    int mg = frame * 1024 + ih * 32 + iw;
    uint4 v = *reinterpret_cast<const uint4*>(qkv + (size_t)mg * 576 + 384 + h * 32 + seg * 8);
    unsigned arr[4] = {v.x, v.y, v.z, v.w};
#pragma unroll
    for (int e = 0; e < 4; e++) {
      Vs[(seg * 8 + e * 2) * PVS + j]     = (unsigned short)(arr[e] & 0xffffu);
      Vs[(seg * 8 + e * 2 + 1) * PVS + j] = (unsigned short)(arr[e] >> 16);
    }
  }
  for (int u = tid; u < 32 * (PVS - 196); u += 256) {
    int dd = u / (PVS - 196), c = 196 + u % (PVS - 196);
    Vs[dd * PVS + c] = 0;
  }
  {
    int q = tid >> 2, seg = tid & 3;
    int qy = ty * 8 + (q >> 3), qx = tx * 8 + (q & 7);
    int mg = frame * 1024 + qy * 32 + qx;
    uint4 v = *reinterpret_cast<const uint4*>(qkv + (size_t)mg * 576 + h * 32 + seg * 8);
    *reinterpret_cast<uint4*>(&Qs[q * PKS + seg * 8]) = v;
  }
  __syncthreads();

  int w = tid >> 6;
  int lane = tid & 63;
  int c = lane & 15;
  int lk = lane >> 4;

  bf16x8 aq = *reinterpret_cast<const bf16x8*>(&Qs[(w * 16 + c) * PKS + lk * 8]);
  f32x4 sc[14];
#pragma unroll
  for (int f = 0; f < 14; f++) {
    bf16x8 bk = *reinterpret_cast<const bf16x8*>(&Ks[(f * 16 + c) * PKS + lk * 8]);
    sc[f] = __builtin_amdgcn_mfma_f32_16x16x32_bf16(aq, bk, (f32x4){0.f, 0.f, 0.f, 0.f}, 0, 0, 0);
  }

#pragma unroll
  for (int f = 0; f < 14; f++) {
    int key = f * 16 + c;
    int a = key / 14, bb = key - a * 14;
    int ih = base_h + a, iw = base_w + bb;
    bool keyok = key < 196;
#pragma unroll
    for (int r = 0; r < 4; r++) {
      int qloc = w * 16 + lk * 4 + r;
      int qy = ty * 8 + (qloc >> 3), qx = tx * 8 + (qloc & 7);
      int sh = min(max(qy - 3, 0), HH - 7);
      int sw = min(max(qx - 3, 0), WW - 7);
      bool valid = keyok && ((unsigned)(ih - sh) < 7u) && ((unsigned)(iw - sw) < 7u);
      int bidx = valid ? (ih - qy + 6) * 13 + (iw - qx + 6) : 0;
      float s = sc[f][r] * ATT_SCALE + rb[bidx];
      sc[f][r] = valid ? s : -1e30f;
    }
  }

  float sm[4];
#pragma unroll
  for (int r = 0; r < 4; r++) {
    float m = sc[0][r];
#pragma unroll
    for (int f = 1; f < 14; f++) m = fmaxf(m, sc[f][r]);
    for (int off = 8; off; off >>= 1) m = fmaxf(m, __shfl_xor(m, off));
    float s = 0.f;
#pragma unroll
    for (int f = 0; f < 14; f++) { float e = __expf(sc[f][r] - m); sc[f][r] = e; s += e; }
    for (int off = 8; off; off >>= 1) s += __shfl_xor(s, off);
    sm[r] = 1.0f / s;
  }
#pragma unroll
  for (int f = 0; f < 14; f++)
#pragma unroll
    for (int r = 0; r < 4; r++)
      Ps[(w * 16 + lk * 4 + r) * PVS + f * 16 + c] = f2us(sc[f][r] * sm[r]);
  __syncthreads();

  f32x4 oacc[2] = {(f32x4){0.f, 0.f, 0.f, 0.f}, (f32x4){0.f, 0.f, 0.f, 0.f}};
#pragma unroll
  for (int kt = 0; kt < 7; kt++) {
    bf16x8 ap = *reinterpret_cast<const bf16x8*>(&Ps[(w * 16 + c) * PVS + kt * 32 + lk * 8]);
#pragma unroll
    for (int dt = 0; dt < 2; dt++) {
      bf16x8 bv = *reinterpret_cast<const bf16x8*>(&Vs[(dt * 16 + c) * PVS + kt * 32 + lk * 8]);
      oacc[dt] = __builtin_amdgcn_mfma_f32_16x16x32_bf16(ap, bv, oacc[dt], 0, 0, 0);
    }
  }

#pragma unroll
  for (int dt = 0; dt < 2; dt++)
#pragma unroll
    for (int r = 0; r < 4; r++) {
      int qloc = w * 16 + lk * 4 + r;
      int qy = ty * 8 + (qloc >> 3), qx = tx * 8 + (qloc & 7);
      int mg = frame * 1024 + qy * 32 + qx;
      O[(size_t)mg * CC + h * 32 + dt * 16 + c] = f2b(oacc[dt][r]);
    }
}

// ---------------------------------------------------------------------------
extern "C" void kernel_launch(void* const* d_in, const int* in_sizes, int n_in,
                              void* d_out, int out_size, void* d_ws, size_t ws_size,
                              hipStream_t stream) {
  const void* x        = d_in[0];
  const void* pos_emb  = d_in[1];
  const void* t_ln1_g  = d_in[2];
  const void* t_ln1_b  = d_in[3];
  const void* t_qkv_w  = d_in[4];
  const void* t_out_w  = d_in[5];
  const void* t_out_b  = d_in[6];
  const void* t_ln2_g  = d_in[7];
  const void* t_ln2_b  = d_in[8];
  const void* t_fc1_w  = d_in[9];
  const void* t_fc1_b  = d_in[10];
  const void* t_fc2_w  = d_in[11];
  const void* t_fc2_b  = d_in[12];
  const void* t_lnf_g  = d_in[13];
  const void* t_lnf_b  = d_in[14];
  const void* s_ln1_g  = d_in[15];
  const void* s_ln1_b  = d_in[16];
  const void* s_qkv_w  = d_in[17];
  const void* s_qkv_b  = d_in[18];
  const void* s_rpb    = d_in[19];
  const void* s_proj_w = d_in[20];
  const void* s_proj_b = d_in[21];
  const void* s_ln2_g  = d_in[22];
  const void* s_ln2_b  = d_in[23];
  const void* s_fc1_w  = d_in[24];
  const void* s_fc1_b  = d_in[25];
  const void* s_fc2_w  = d_in[26];
  const void* s_fc2_b  = d_in[27];

  // Workspace: [0,SZ) f32 T/S | [SZ,2SZ) f32 X1T | [2SZ,2.5SZ) bf16 Y |
  // [2.5SZ,3SZ) bf16 O | [3SZ,5SZ) bf16 QKV/Hb | [5SZ] dfl | WT bf16.
  float* ws = (float*)d_ws;
  const size_t SZ = (size_t)NTOK * CC;
  const size_t need = (5 * SZ + 4 + 442368 + 16) * sizeof(float);
  if (ws_size < need) return;

  float* T   = ws;
  float* X1T = ws + SZ;
  bf16*  Y   = (bf16*)(ws + 2 * SZ);
  bf16*  O   = (bf16*)(ws + 2 * SZ + SZ / 2);
  bf16*  QKV = (bf16*)(ws + 3 * SZ);
  bf16*  Hb  = QKV;
  float* S   = T;
  int*   dfl = (int*)(ws + 5 * SZ);
  bf16*  WT  = (bf16*)(ws + 5 * SZ + 4);

  dim3 blk256(256);

  // fused weight-transpose (216 tiles) + build_ln1 (2048 blocks)
  prep_kernel<<<216 + 2048, blk256, 0, stream>>>(
      (const unsigned short*)x,
      t_qkv_w, t_out_w, t_fc1_w, t_fc2_w, s_qkv_w, s_proj_w, s_fc1_w, s_fc2_w,
      WT, dfl, pos_emb, t_ln1_g, t_ln1_b, T, Y);

  // ---- Time transformer ----
  gemm_kernel<2, false, false, false, true, false><<<dim3(9, 64), blk256, 0, stream>>>(
      Y, WT + WOFF_TQKV, nullptr, nullptr, QKV, nullptr, NTOK, 3 * CC, CC, dfl);
  time_attn_kernel<<<1024, 192, 0, stream>>>(QKV, O);
  gemm_kernel<1, true, false, true, false, false><<<dim3(3, 128), blk256, 0, stream>>>(
      O, WT + WOFF_TOUT, t_out_b, T, T, nullptr, NTOK, CC, CC, dfl);
  ln_kernel<<<NTOK / 4, blk256, 0, stream>>>(T, Y, t_ln2_g, t_ln2_b, NTOK, dfl);
  gemm_kernel<2, true, true, false, true, false><<<dim3(12, 64), blk256, 0, stream>>>(
      Y, WT + WOFF_TFC1, t_fc1_b, nullptr, Hb, nullptr, NTOK, HID, CC, dfl);
  gemm_kernel<1, true, false, true, false, false><<<dim3(3, 128), blk256, 0, stream>>>(
      Hb, WT + WOFF_TFC2, t_fc2_b, T, T, nullptr, NTOK, CC, HID, dfl);
  epi_ln1_kernel<<<NTOK / 4, blk256, 0, stream>>>(
      T, x, t_lnf_g, t_lnf_b, s_ln1_g, s_ln1_b, X1T, Y, dfl);

  // ---- Space transformer ----
  gemm_kernel<2, true, false, false, true, false><<<dim3(9, 64), blk256, 0, stream>>>(
      Y, WT + WOFF_SQKV, s_qkv_b, nullptr, QKV, nullptr, NTOK, 3 * CC, CC, dfl);
  nat_attn_kernel<<<768, blk256, 0, stream>>>(QKV, s_rpb, O, dfl);
  gemm_kernel<1, true, false, true, false, false><<<dim3(3, 128), blk256, 0, stream>>>(
      O, WT + WOFF_SPROJ, s_proj_b, X1T, S, nullptr, NTOK, CC, CC, dfl);
  ln_kernel<<<NTOK / 4, blk256, 0, stream>>>(S, Y, s_ln2_g, s_ln2_b, NTOK, dfl);
  gemm_kernel<2, true, true, false, true, false><<<dim3(12, 64), blk256, 0, stream>>>(
      Y, WT + WOFF_SFC1, s_fc1_b, nullptr, Hb, nullptr, NTOK, HID, CC, dfl);
  gemm_kernel<1, true, false, true, false, true><<<dim3(3, 128), blk256, 0, stream>>>(
      Hb, WT + WOFF_SFC2, s_fc2_b, S, d_out, X1T, NTOK, CC, HID, dfl);
}

// Round 13
// 266.886 us; speedup vs baseline: 3.1466x; 1.0208x over previous
//
#include <hip/hip_runtime.h>
#include <hip/hip_bf16.h>
#include <math.h>

typedef __hip_bfloat16 bf16;
typedef short bf16x8 __attribute__((ext_vector_type(8)));
typedef float f32x4 __attribute__((ext_vector_type(4)));

__device__ __forceinline__ float b2f(bf16 v) { return __bfloat162float(v); }
__device__ __forceinline__ bf16 f2b(float v) { return __float2bfloat16(v); }
__device__ __forceinline__ float us2f(unsigned short u) {
  return __uint_as_float(((unsigned)u) << 16);
}
__device__ __forceinline__ unsigned short f2us(float f) {
  bf16 h = __float2bfloat16(f);
  return *reinterpret_cast<unsigned short*>(&h);
}
__device__ __forceinline__ float ldin(const void* p, size_t i, int f32) {
  return f32 ? ((const float*)p)[i] : b2f(((const bf16*)p)[i]);
}

#define CC 192
#define DD 8
#define HH 32
#define WW 32
#define NHEAD 6
#define HDIM 32
#define HID 768
#define NTOK 8192
#define ATT_SCALE 0.17677669529663687f

#define WOFF_TQKV  0
#define WOFF_TOUT  110592
#define WOFF_TFC1  147456
#define WOFF_TFC2  294912
#define WOFF_SQKV  442368
#define WOFF_SPROJ 552960
#define WOFF_SFC1  589824
#define WOFF_SFC2  737280

// ---------------------------------------------------------------------------
// Fused prep (proven r12): blocks [0,216) coalesced weight transpose;
// blocks [216,216+2048) build_ln1. Block 0 publishes dtype flag.
// ---------------------------------------------------------------------------
__global__ void __launch_bounds__(256) prep_kernel(
    const unsigned short* __restrict__ xu,
    const void* w0, const void* w1, const void* w2, const void* w3,
    const void* w4, const void* w5, const void* w6, const void* w7,
    bf16* __restrict__ WT, int* __restrict__ flag,
    const void* __restrict__ pos,
    const void* __restrict__ g, const void* __restrict__ b,
    float* __restrict__ T, bf16* __restrict__ Y) {
  __shared__ int cnt[4];
  __shared__ unsigned short tile_s[64 * 66];
  {
    float v = fabsf(us2f(xu[threadIdx.x]));
    bool insane = !((v == 0.0f) || (v > 9.5e-7f && v < 64.0f));
    unsigned long long m = __ballot(insane);
    if ((threadIdx.x & 63) == 0) cnt[threadIdx.x >> 6] = __popcll(m);
  }
  __syncthreads();
  int f32 = (cnt[0] + cnt[1] + cnt[2] + cnt[3]) > 32;
  if (blockIdx.x == 0 && threadIdx.x == 0) *flag = f32;

  int blk = blockIdx.x;
  int w = threadIdx.x >> 6, lane = threadIdx.x & 63;

  if (blk < 216) {
    const int cumt[8] = {27, 36, 72, 108, 135, 144, 180, 216};
    const int Karr[8] = {192, 192, 192, 768, 192, 192, 192, 768};
    const int Narr[8] = {576, 192, 768, 192, 576, 192, 768, 192};
    const int warr[8] = {WOFF_TQKV, WOFF_TOUT, WOFF_TFC1, WOFF_TFC2,
                         WOFF_SQKV, WOFF_SPROJ, WOFF_SFC1, WOFF_SFC2};
    const void* srcs[8] = {w0, w1, w2, w3, w4, w5, w6, w7};
    int m = 0;
    while (blk >= cumt[m]) m++;
    int lt = blk - (m ? cumt[m - 1] : 0);
    int K = Karr[m], N = Narr[m];
    int ncol = N >> 6;
    int kt = lt / ncol, nt = lt - kt * ncol;
    int k0 = kt * 64, n0 = nt * 64;
    const void* src = srcs[m];
#pragma unroll
    for (int i = 0; i < 16; i++) {
      int k = w * 16 + i;
      tile_s[k * 66 + lane] = f2us(ldin(src, (size_t)(k0 + k) * N + n0 + lane, f32));
    }
    __syncthreads();
    unsigned short* dst = reinterpret_cast<unsigned short*>(WT) + warr[m];
#pragma unroll
    for (int i = 0; i < 16; i++) {
      int n = w * 16 + i;
      dst[(size_t)(n0 + n) * K + k0 + lane] = tile_s[lane * 66 + n];
    }
    return;
  }

  int row = (blk - 216) * 4 + w;
  if (row >= NTOK) return;
  int d = row & 7, hw = row >> 3;
  float v[3];
#pragma unroll
  for (int e = 0; e < 3; e++) {
    int c = lane + e * 64;
    v[e] = ldin(xu, (size_t)((c << 3) + d) * 1024 + hw, f32) +
           ldin(pos, (size_t)d * CC + c, f32);
  }
  float* tr = T + (size_t)row * CC;
#pragma unroll
  for (int e = 0; e < 3; e++) tr[lane + e * 64] = v[e];
  float s = v[0] + v[1] + v[2];
  for (int off = 32; off; off >>= 1) s += __shfl_xor(s, off);
  float mean = s * (1.0f / CC);
  float d0 = v[0] - mean, d1 = v[1] - mean, d2 = v[2] - mean;
  float q = d0 * d0 + d1 * d1 + d2 * d2;
  for (int off = 32; off; off >>= 1) q += __shfl_xor(q, off);
  float rstd = rsqrtf(q * (1.0f / CC) + 1e-5f);
  bf16* o = Y + (size_t)row * CC;
  o[lane]       = f2b(d0 * rstd * ldin(g, lane, f32)       + ldin(b, lane, f32));
  o[lane + 64]  = f2b(d1 * rstd * ldin(g, lane + 64, f32)  + ldin(b, lane + 64, f32));
  o[lane + 128] = f2b(d2 * rstd * ldin(g, lane + 128, f32) + ldin(b, lane + 128, f32));
}

// ---------------------------------------------------------------------------
// MFMA GEMM (proven r7): A bf16 [M,K], WT bf16 [N,K]. BK=64. TM in {1,2}.
// FINAL: dst[col*NTOK+row] = v + X2[row*CC+col] (dtype by flag)
// ---------------------------------------------------------------------------
template <int TM, bool BIAS, bool GELU, bool RES, bool OUTBF, bool FINAL>
__global__ void gemm_kernel(const bf16* __restrict__ A, const bf16* __restrict__ WT,
                            const void* __restrict__ bias, const float* __restrict__ R,
                            void* __restrict__ Cout, const float* __restrict__ X2,
                            int M, int N, int K, const int* __restrict__ dfl) {
  int f32 = *dfl;
  __shared__ __align__(16) unsigned short As[TM * 64 * 72];
  __shared__ __align__(16) unsigned short Bs[64 * 72];
  int bm = blockIdx.y * (TM * 64), bn = blockIdx.x * 64;
  int tid = threadIdx.x;
  int w = tid >> 6;
  int lane = tid & 63;
  int lm = lane & 15;
  int lk = lane >> 4;

  f32x4 acc[TM][4];
#pragma unroll
  for (int i = 0; i < TM; i++)
#pragma unroll
    for (int j = 0; j < 4; j++) acc[i][j] = (f32x4){0.f, 0.f, 0.f, 0.f};

  const unsigned short* Au = reinterpret_cast<const unsigned short*>(A);
  const unsigned short* Wu = reinterpret_cast<const unsigned short*>(WT);

  for (int k0 = 0; k0 < K; k0 += 64) {
#pragma unroll
    for (int u = 0; u < TM * 2; u++) {
      int unit = tid + u * 256;
      int row = unit >> 3, seg = unit & 7;
      uint4 v = *reinterpret_cast<const uint4*>(
          &Au[(size_t)(bm + row) * K + k0 + seg * 8]);
      *reinterpret_cast<uint4*>(&As[row * 72 + seg * 8]) = v;
    }
#pragma unroll
    for (int u = 0; u < 2; u++) {
      int unit = tid + u * 256;
      int n = unit >> 3, seg = unit & 7;
      uint4 v = *reinterpret_cast<const uint4*>(
          &Wu[(size_t)(bn + n) * K + k0 + seg * 8]);
      *reinterpret_cast<uint4*>(&Bs[n * 72 + seg * 8]) = v;
    }
    __syncthreads();

#pragma unroll
    for (int kc = 0; kc < 2; kc++) {
      bf16x8 af[TM], bfr[4];
#pragma unroll
      for (int tm = 0; tm < TM; tm++)
        af[tm] = *reinterpret_cast<const bf16x8*>(
            &As[(w * (TM * 16) + tm * 16 + lm) * 72 + kc * 32 + lk * 8]);
#pragma unroll
      for (int tn = 0; tn < 4; tn++)
        bfr[tn] = *reinterpret_cast<const bf16x8*>(
            &Bs[(tn * 16 + lm) * 72 + kc * 32 + lk * 8]);
#pragma unroll
      for (int tm = 0; tm < TM; tm++)
#pragma unroll
        for (int tn = 0; tn < 4; tn++)
          acc[tm][tn] = __builtin_amdgcn_mfma_f32_16x16x32_bf16(
              af[tm], bfr[tn], acc[tm][tn], 0, 0, 0);
    }
    __syncthreads();
  }

#pragma unroll
  for (int tn = 0; tn < 4; tn++) {
    int col = bn + tn * 16 + lm;
    float bv = BIAS ? ldin(bias, col, f32) : 0.f;
#pragma unroll
    for (int tm = 0; tm < TM; tm++) {
      int row0 = bm + w * (TM * 16) + tm * 16 + lk * 4;
#pragma unroll
      for (int r = 0; r < 4; r++) {
        int row = row0 + r;
        float v = acc[tm][tn][r];
        if (BIAS) v += bv;
        if (GELU) v = 0.5f * v * (1.0f + erff(v * 0.70710678118654752f));
        size_t idx = (size_t)row * N + col;
        if (RES) v += R[idx];
        if (FINAL) {
          float o = v + X2[(size_t)row * CC + col];
          if (f32) ((float*)Cout)[(size_t)col * NTOK + row] = o;
          else     ((bf16*)Cout)[(size_t)col * NTOK + row] = f2b(o);
        } else if (OUTBF) {
          ((bf16*)Cout)[idx] = f2b(v);
        } else {
          ((float*)Cout)[idx] = v;
        }
      }
    }
  }
}

// ---------------------------------------------------------------------------
// NEW: N=192 GEMM with fused row-LayerNorm epilogue.
// Block = 16 rows x 192 cols; grid 512 (2/CU); 4 waves, wave = 48 cols
// (3 MFMA frags). K=192 (BK=64, 3 iters). Epilogue: v = acc+bias+R ->
// Fout fp32; two-pass LN (16-lane shfl + cross-wave LDS) -> Yout bf16.
// LDS ~30 KB. W-tile 73KB/block re-read is L2-resident.
// ---------------------------------------------------------------------------
__global__ void __launch_bounds__(256) gemm_ln16_kernel(
    const bf16* __restrict__ A, const bf16* __restrict__ WT,
    const void* __restrict__ bias, const float* __restrict__ R,
    float* __restrict__ Fout, bf16* __restrict__ Yout,
    const void* __restrict__ g, const void* __restrict__ b,
    const int* __restrict__ dfl) {
  int f32 = *dfl;
  __shared__ __align__(16) unsigned short As[16 * 72];
  __shared__ __align__(16) unsigned short Bs[192 * 72];
  __shared__ float red[16][4];
  int bm = blockIdx.x * 16;
  int tid = threadIdx.x;
  int w = tid >> 6, lane = tid & 63, lm = lane & 15, lk = lane >> 4;

  f32x4 acc[3];
#pragma unroll
  for (int j = 0; j < 3; j++) acc[j] = (f32x4){0.f, 0.f, 0.f, 0.f};

  const unsigned short* Au = reinterpret_cast<const unsigned short*>(A);
  const unsigned short* Wu = reinterpret_cast<const unsigned short*>(WT);

  for (int k0 = 0; k0 < 192; k0 += 64) {
    if (tid < 128) {
      int row = tid >> 3, seg = tid & 7;
      uint4 v = *reinterpret_cast<const uint4*>(
          &Au[(size_t)(bm + row) * 192 + k0 + seg * 8]);
      *reinterpret_cast<uint4*>(&As[row * 72 + seg * 8]) = v;
    }
#pragma unroll
    for (int u = 0; u < 6; u++) {
      int unit = tid + u * 256;
      int n = unit >> 3, seg = unit & 7;
      uint4 v = *reinterpret_cast<const uint4*>(
          &Wu[(size_t)n * 192 + k0 + seg * 8]);
      *reinterpret_cast<uint4*>(&Bs[n * 72 + seg * 8]) = v;
    }
    __syncthreads();
#pragma unroll
    for (int kc = 0; kc < 2; kc++) {
      bf16x8 af = *reinterpret_cast<const bf16x8*>(&As[lm * 72 + kc * 32 + lk * 8]);
#pragma unroll
      for (int t = 0; t < 3; t++) {
        bf16x8 bfr = *reinterpret_cast<const bf16x8*>(
            &Bs[(w * 48 + t * 16 + lm) * 72 + kc * 32 + lk * 8]);
        acc[t] = __builtin_amdgcn_mfma_f32_16x16x32_bf16(af, bfr, acc[t], 0, 0, 0);
      }
    }
    __syncthreads();
  }

  // values: col = w*48 + t*16 + lm ; row = bm + lk*4 + r
  float v[3][4];
  float psum[4];
#pragma unroll
  for (int r = 0; r < 4; r++) psum[r] = 0.f;
#pragma unroll
  for (int t = 0; t < 3; t++) {
    int col = w * 48 + t * 16 + lm;
    float bv = ldin(bias, col, f32);
#pragma unroll
    for (int r = 0; r < 4; r++) {
      int row = bm + lk * 4 + r;
      float val = acc[t][r] + bv + R[(size_t)row * CC + col];
      v[t][r] = val;
      psum[r] += val;
    }
  }
  // pass 1: row sums
#pragma unroll
  for (int r = 0; r < 4; r++) {
    float s = psum[r];
    for (int off = 1; off < 16; off <<= 1) s += __shfl_xor(s, off);
    if (lm == 0) red[lk * 4 + r][w] = s;
  }
  __syncthreads();
  float mean[4];
#pragma unroll
  for (int r = 0; r < 4; r++) {
    int rl = lk * 4 + r;
    mean[r] = (red[rl][0] + red[rl][1] + red[rl][2] + red[rl][3]) * (1.0f / CC);
  }
  __syncthreads();
  // pass 2: centered sumsq
#pragma unroll
  for (int r = 0; r < 4; r++) {
    float q = 0.f;
#pragma unroll
    for (int t = 0; t < 3; t++) { float d = v[t][r] - mean[r]; q += d * d; }
    for (int off = 1; off < 16; off <<= 1) q += __shfl_xor(q, off);
    if (lm == 0) red[lk * 4 + r][w] = q;
  }
  __syncthreads();
#pragma unroll
  for (int r = 0; r < 4; r++) {
    int rl = lk * 4 + r;
    float q = red[rl][0] + red[rl][1] + red[rl][2] + red[rl][3];
    float rstd = rsqrtf(q * (1.0f / CC) + 1e-5f);
    int row = bm + rl;
#pragma unroll
    for (int t = 0; t < 3; t++) {
      int col = w * 48 + t * 16 + lm;
      float val = v[t][r];
      Fout[(size_t)row * CC + col] = val;
      Yout[(size_t)row * CC + col] =
          f2b((val - mean[r]) * rstd * ldin(g, col, f32) + ldin(b, col, f32));
    }
  }
}

// ---------------------------------------------------------------------------
// Time attention (proven): one block per sequence n (1024), 192 threads
// ---------------------------------------------------------------------------
__global__ void time_attn_kernel(const bf16* __restrict__ qkv, bf16* __restrict__ O) {
  __shared__ float q[NHEAD][DD][HDIM];
  __shared__ float k[NHEAD][DD][HDIM];
  __shared__ float v[NHEAD][DD][HDIM];
  __shared__ float p[NHEAD][DD][DD];
  int n = blockIdx.x;
  int head = threadIdx.x >> 5;
  int dd = threadIdx.x & 31;
  for (int s = 0; s < DD; s++) {
    const bf16* row = qkv + (size_t)(n * DD + s) * (3 * CC);
    q[head][s][dd] = b2f(row[head * HDIM + dd]);
    k[head][s][dd] = b2f(row[CC + head * HDIM + dd]);
    v[head][s][dd] = b2f(row[2 * CC + head * HDIM + dd]);
  }
  __syncthreads();
  for (int pair = dd; pair < 64; pair += 32) {
    int sq = pair >> 3, sk = pair & 7;
    float sum = 0.f;
#pragma unroll
    for (int e = 0; e < HDIM; e++) sum += q[head][sq][e] * k[head][sk][e];
    p[head][sq][sk] = sum * ATT_SCALE;
  }
  __syncthreads();
  if (dd < DD) {
    float mx = -1e30f;
    for (int sk = 0; sk < DD; sk++) mx = fmaxf(mx, p[head][dd][sk]);
    float sum = 0.f;
    for (int sk = 0; sk < DD; sk++) { float e = expf(p[head][dd][sk] - mx); p[head][dd][sk] = e; sum += e; }
    float inv = 1.0f / sum;
    for (int sk = 0; sk < DD; sk++) p[head][dd][sk] *= inv;
  }
  __syncthreads();
  for (int sq = 0; sq < DD; sq++) {
    float sum = 0.f;
#pragma unroll
    for (int sk = 0; sk < DD; sk++) sum += p[head][sq][sk] * v[head][sk][dd];
    O[(size_t)(n * DD + sq) * CC + head * HDIM + dd] = f2b(sum);
  }
}

// ---------------------------------------------------------------------------
// Fused time epilogue + space ln1 (proven r7)
// ---------------------------------------------------------------------------
__global__ void epi_ln1_kernel(const float* __restrict__ T, const void* __restrict__ x,
                               const void* __restrict__ gf, const void* __restrict__ bf,
                               const void* __restrict__ g1, const void* __restrict__ b1,
                               float* __restrict__ X1T, bf16* __restrict__ Y,
                               const int* __restrict__ dfl) {
  int f32 = *dfl;
  int wave = (blockIdx.x * blockDim.x + threadIdx.x) >> 6;
  int lane = threadIdx.x & 63;
  if (wave >= NTOK) return;
  const float* r = T + (size_t)wave * CC;
  float v0 = r[lane], v1 = r[lane + 64], v2 = r[lane + 128];
  float s = v0 + v1 + v2;
  for (int off = 32; off; off >>= 1) s += __shfl_xor(s, off);
  float mean = s * (1.0f / CC);
  float d0 = v0 - mean, d1 = v1 - mean, d2 = v2 - mean;
  float q = d0 * d0 + d1 * d1 + d2 * d2;
  for (int off = 32; off; off >>= 1) q += __shfl_xor(q, off);
  float rstd = rsqrtf(q * (1.0f / CC) + 1e-5f);
  int d = wave & 7, hw = wave >> 3;
  int m = d * 1024 + hw;
  float xv[3];
#pragma unroll
  for (int e = 0; e < 3; e++) {
    int c = lane + e * 64;
    float dv = (e == 0 ? d0 : (e == 1 ? d1 : d2));
    float normed = dv * rstd * ldin(gf, c, f32) + ldin(bf, c, f32);
    xv[e] = ldin(x, (size_t)((c << 3) + d) * 1024 + hw, f32) + normed;
  }
  float* o = X1T + (size_t)m * CC;
#pragma unroll
  for (int e = 0; e < 3; e++) o[lane + e * 64] = xv[e];
  float s2 = xv[0] + xv[1] + xv[2];
  for (int off = 32; off; off >>= 1) s2 += __shfl_xor(s2, off);
  float mean2 = s2 * (1.0f / CC);
  float e0 = xv[0] - mean2, e1 = xv[1] - mean2, e2 = xv[2] - mean2;
  float q2 = e0 * e0 + e1 * e1 + e2 * e2;
  for (int off = 32; off; off >>= 1) q2 += __shfl_xor(q2, off);
  float rstd2 = rsqrtf(q2 * (1.0f / CC) + 1e-5f);
  bf16* y = Y + (size_t)m * CC;
  y[lane]       = f2b(e0 * rstd2 * ldin(g1, lane, f32)       + ldin(b1, lane, f32));
  y[lane + 64]  = f2b(e1 * rstd2 * ldin(g1, lane + 64, f32)  + ldin(b1, lane + 64, f32));
  y[lane + 128] = f2b(e2 * rstd2 * ldin(g1, lane + 128, f32) + ldin(b1, lane + 128, f32));
}

// ---------------------------------------------------------------------------
// MFMA NAT attention (proven r6). Block = (frame, 8x8 tile, head), 768 blocks.
// ---------------------------------------------------------------------------
#define NKEY 224
#define PKS 40
#define PVS 232
__global__ void nat_attn_kernel(const bf16* __restrict__ qkv, const void* __restrict__ rpb,
                                bf16* __restrict__ O, const int* __restrict__ dfl) {
  int f32 = *dfl;
  __shared__ __align__(16) unsigned short Ks[NKEY * PKS];
  __shared__ __align__(16) unsigned short Vs[32 * PVS];
  __shared__ __align__(16) unsigned short Qs[64 * PKS];
  __shared__ __align__(16) unsigned short Ps[64 * PVS];
  __shared__ float rb[176];

  int blk = blockIdx.x;
  int frame = blk & 7;
  int rest = blk >> 3;
  int h = rest % 6;
  int tile = rest / 6;
  int ty = tile >> 2, tx = tile & 3;
  int base_h = min(max(ty * 8 - 3, 0), HH - 7);
  int base_w = min(max(tx * 8 - 3, 0), WW - 7);

  int tid = threadIdx.x;

  for (int i = tid; i < 169; i += 256) rb[i] = ldin(rpb, (size_t)h * 169 + i, f32);
  for (int u = tid; u < 784; u += 256) {
    int j = u >> 2, seg = u & 3;
    int a = j / 14, bb = j - a * 14;
    int ih = min(base_h + a, HH - 1), iw = min(base_w + bb, WW - 1);
    int mg = frame * 1024 + ih * 32 + iw;
    uint4 v = *reinterpret_cast<const uint4*>(qkv + (size_t)mg * 576 + 192 + h * 32 + seg * 8);
    *reinterpret_cast<uint4*>(&Ks[j * PKS + seg * 8]) = v;
  }
  for (int u = tid; u < 784; u += 256) {
    int j = u >> 2, seg = u & 3;
    int a = j / 14, bb = j - a * 14;
    int ih = min(base_h + a, HH - 1), iw = min(base_w + bb, WW - 1);
    int mg = frame * 1024 + ih * 32 + iw;
    uint4 v = *reinterpret_cast<const uint4*>(qkv + (size_t)mg * 576 + 384 + h * 32 + seg * 8);
    unsigned arr[4] = {v.x, v.y, v.z, v.w};
#pragma unroll
    for (int e = 0; e < 4; e++) {
      Vs[(seg * 8 + e * 2) * PVS + j]     = (unsigned short)(arr[e] & 0xffffu);
      Vs[(seg * 8 + e * 2 + 1) * PVS + j] = (unsigned short)(arr[e] >> 16);
    }
  }
  for (int u = tid; u < 32 * (PVS - 196); u += 256) {
    int dd = u / (PVS - 196), c = 196 + u % (PVS - 196);
    Vs[dd * PVS + c] = 0;
  }
  {
    int q = tid >> 2, seg = tid & 3;
    int qy = ty * 8 + (q >> 3), qx = tx * 8 + (q & 7);
    int mg = frame * 1024 + qy * 32 + qx;
    uint4 v = *reinterpret_cast<const uint4*>(qkv + (size_t)mg * 576 + h * 32 + seg * 8);
    *reinterpret_cast<uint4*>(&Qs[q * PKS + seg * 8]) = v;
  }
  __syncthreads();

  int w = tid >> 6;
  int lane = tid & 63;
  int c = lane & 15;
  int lk = lane >> 4;

  bf16x8 aq = *reinterpret_cast<const bf16x8*>(&Qs[(w * 16 + c) * PKS + lk * 8]);
  f32x4 sc[14];
#pragma unroll
  for (int f = 0; f < 14; f++) {
    bf16x8 bk = *reinterpret_cast<const bf16x8*>(&Ks[(f * 16 + c) * PKS + lk * 8]);
    sc[f] = __builtin_amdgcn_mfma_f32_16x16x32_bf16(aq, bk, (f32x4){0.f, 0.f, 0.f, 0.f}, 0, 0, 0);
  }

#pragma unroll
  for (int f = 0; f < 14; f++) {
    int key = f * 16 + c;
    int a = key / 14, bb = key - a * 14;
    int ih = base_h + a, iw = base_w + bb;
    bool keyok = key < 196;
#pragma unroll
    for (int r = 0; r < 4; r++) {
      int qloc = w * 16 + lk * 4 + r;
      int qy = ty * 8 + (qloc >> 3), qx = tx * 8 + (qloc & 7);
      int sh = min(max(qy - 3, 0), HH - 7);
      int sw = min(max(qx - 3, 0), WW - 7);
      bool valid = keyok && ((unsigned)(ih - sh) < 7u) && ((unsigned)(iw - sw) < 7u);
      int bidx = valid ? (ih - qy + 6) * 13 + (iw - qx + 6) : 0;
      float s = sc[f][r] * ATT_SCALE + rb[bidx];
      sc[f][r] = valid ? s : -1e30f;
    }
  }

  float sm[4];
#pragma unroll
  for (int r = 0; r < 4; r++) {
    float m = sc[0][r];
#pragma unroll
    for (int f = 1; f < 14; f++) m = fmaxf(m, sc[f][r]);
    for (int off = 8; off; off >>= 1) m = fmaxf(m, __shfl_xor(m, off));
    float s = 0.f;
#pragma unroll
    for (int f = 0; f < 14; f++) { float e = __expf(sc[f][r] - m); sc[f][r] = e; s += e; }
    for (int off = 8; off; off >>= 1) s += __shfl_xor(s, off);
    sm[r] = 1.0f / s;
  }
#pragma unroll
  for (int f = 0; f < 14; f++)
#pragma unroll
    for (int r = 0; r < 4; r++)
      Ps[(w * 16 + lk * 4 + r) * PVS + f * 16 + c] = f2us(sc[f][r] * sm[r]);
  __syncthreads();

  f32x4 oacc[2] = {(f32x4){0.f, 0.f, 0.f, 0.f}, (f32x4){0.f, 0.f, 0.f, 0.f}};
#pragma unroll
  for (int kt = 0; kt < 7; kt++) {
    bf16x8 ap = *reinterpret_cast<const bf16x8*>(&Ps[(w * 16 + c) * PVS + kt * 32 + lk * 8]);
#pragma unroll
    for (int dt = 0; dt < 2; dt++) {
      bf16x8 bv = *reinterpret_cast<const bf16x8*>(&Vs[(dt * 16 + c) * PVS + kt * 32 + lk * 8]);
      oacc[dt] = __builtin_amdgcn_mfma_f32_16x16x32_bf16(ap, bv, oacc[dt], 0, 0, 0);
    }
  }

#pragma unroll
  for (int dt = 0; dt < 2; dt++)
#pragma unroll
    for (int r = 0; r < 4; r++) {
      int qloc = w * 16 + lk * 4 + r;
      int qy = ty * 8 + (qloc >> 3), qx = tx * 8 + (qloc & 7);
      int mg = frame * 1024 + qy * 32 + qx;
      O[(size_t)mg * CC + h * 32 + dt * 16 + c] = f2b(oacc[dt][r]);
    }
}

// ---------------------------------------------------------------------------
extern "C" void kernel_launch(void* const* d_in, const int* in_sizes, int n_in,
                              void* d_out, int out_size, void* d_ws, size_t ws_size,
                              hipStream_t stream) {
  const void* x        = d_in[0];
  const void* pos_emb  = d_in[1];
  const void* t_ln1_g  = d_in[2];
  const void* t_ln1_b  = d_in[3];
  const void* t_qkv_w  = d_in[4];
  const void* t_out_w  = d_in[5];
  const void* t_out_b  = d_in[6];
  const void* t_ln2_g  = d_in[7];
  const void* t_ln2_b  = d_in[8];
  const void* t_fc1_w  = d_in[9];
  const void* t_fc1_b  = d_in[10];
  const void* t_fc2_w  = d_in[11];
  const void* t_fc2_b  = d_in[12];
  const void* t_lnf_g  = d_in[13];
  const void* t_lnf_b  = d_in[14];
  const void* s_ln1_g  = d_in[15];
  const void* s_ln1_b  = d_in[16];
  const void* s_qkv_w  = d_in[17];
  const void* s_qkv_b  = d_in[18];
  const void* s_rpb    = d_in[19];
  const void* s_proj_w = d_in[20];
  const void* s_proj_b = d_in[21];
  const void* s_ln2_g  = d_in[22];
  const void* s_ln2_b  = d_in[23];
  const void* s_fc1_w  = d_in[24];
  const void* s_fc1_b  = d_in[25];
  const void* s_fc2_w  = d_in[26];
  const void* s_fc2_b  = d_in[27];

  // Workspace: [0,SZ) f32 T/S | [SZ,2SZ) f32 X1T | [2SZ,2.5SZ) bf16 Y |
  // [2.5SZ,3SZ) bf16 O | [3SZ,5SZ) bf16 QKV/Hb | [5SZ] dfl | WT bf16.
  float* ws = (float*)d_ws;
  const size_t SZ = (size_t)NTOK * CC;
  const size_t need = (5 * SZ + 4 + 442368 + 16) * sizeof(float);
  if (ws_size < need) return;

  float* T   = ws;
  float* X1T = ws + SZ;
  bf16*  Y   = (bf16*)(ws + 2 * SZ);
  bf16*  O   = (bf16*)(ws + 2 * SZ + SZ / 2);
  bf16*  QKV = (bf16*)(ws + 3 * SZ);
  bf16*  Hb  = QKV;
  float* S   = T;
  int*   dfl = (int*)(ws + 5 * SZ);
  bf16*  WT  = (bf16*)(ws + 5 * SZ + 4);

  dim3 blk256(256);

  // fused weight-transpose (216 tiles) + build_ln1 (2048 blocks)
  prep_kernel<<<216 + 2048, blk256, 0, stream>>>(
      (const unsigned short*)x,
      t_qkv_w, t_out_w, t_fc1_w, t_fc2_w, s_qkv_w, s_proj_w, s_fc1_w, s_fc2_w,
      WT, dfl, pos_emb, t_ln1_g, t_ln1_b, T, Y);

  // ---- Time transformer ----
  gemm_kernel<2, false, false, false, true, false><<<dim3(9, 64), blk256, 0, stream>>>(
      Y, WT + WOFF_TQKV, nullptr, nullptr, QKV, nullptr, NTOK, 3 * CC, CC, dfl);
  time_attn_kernel<<<1024, 192, 0, stream>>>(QKV, O);
  // out-proj + residual + t_ln2 fused (512 blocks, full-row tiles)
  gemm_ln16_kernel<<<512, blk256, 0, stream>>>(
      O, WT + WOFF_TOUT, t_out_b, T, T, Y, t_ln2_g, t_ln2_b, dfl);
  gemm_kernel<2, true, true, false, true, false><<<dim3(12, 64), blk256, 0, stream>>>(
      Y, WT + WOFF_TFC1, t_fc1_b, nullptr, Hb, nullptr, NTOK, HID, CC, dfl);
  gemm_kernel<1, true, false, true, false, false><<<dim3(3, 128), blk256, 0, stream>>>(
      Hb, WT + WOFF_TFC2, t_fc2_b, T, T, nullptr, NTOK, CC, HID, dfl);
  epi_ln1_kernel<<<NTOK / 4, blk256, 0, stream>>>(
      T, x, t_lnf_g, t_lnf_b, s_ln1_g, s_ln1_b, X1T, Y, dfl);

  // ---- Space transformer ----
  gemm_kernel<2, true, false, false, true, false><<<dim3(9, 64), blk256, 0, stream>>>(
      Y, WT + WOFF_SQKV, s_qkv_b, nullptr, QKV, nullptr, NTOK, 3 * CC, CC, dfl);
  nat_attn_kernel<<<768, blk256, 0, stream>>>(QKV, s_rpb, O, dfl);
  // proj + residual + s_ln2 fused
  gemm_ln16_kernel<<<512, blk256, 0, stream>>>(
      O, WT + WOFF_SPROJ, s_proj_b, X1T, S, Y, s_ln2_g, s_ln2_b, dfl);
  gemm_kernel<2, true, true, false, true, false><<<dim3(12, 64), blk256, 0, stream>>>(
      Y, WT + WOFF_SFC1, s_fc1_b, nullptr, Hb, nullptr, NTOK, HID, CC, dfl);
  gemm_kernel<1, true, false, true, false, true><<<dim3(3, 128), blk256, 0, stream>>>(
      Hb, WT + WOFF_SFC2, s_fc2_b, S, d_out, X1T, NTOK, CC, HID, dfl);
}